// Round 1
// baseline (2308.541 us; speedup 1.0000x reference)
//
#include <hip/hip_runtime.h>

#define BLK 256

__global__ void k_deg_init(float* __restrict__ deg, int n) {
  int i = blockIdx.x * blockDim.x + threadIdx.x;
  if (i < n) deg[i] = 1.0f;
}

__global__ void k_deg_count(const int* __restrict__ dst, float* __restrict__ deg, int e) {
  int i = blockIdx.x * blockDim.x + threadIdx.x;
  if (i < e) atomicAdd(&deg[dst[i]], 1.0f);
}

__global__ void k_dinv(float* __restrict__ deg, int n) {
  int i = blockIdx.x * blockDim.x + threadIdx.x;
  if (i < n) deg[i] = rsqrtf(deg[i]);
}

// h = x @ W1 ; hs1 = h * dinv ; agg1 = hs1 (self-loop init)
__global__ void k_transform1(const float* __restrict__ x, const float* __restrict__ W1,
                             const float* __restrict__ dinv,
                             float* __restrict__ hs1, float* __restrict__ agg1, int n) {
  __shared__ float w[160];
  int t = threadIdx.x;
  if (t < 160) w[t] = W1[t];
  __syncthreads();
  int i = blockIdx.x * blockDim.x + t;
  if (i >= n) return;
  float xi[10];
#pragma unroll
  for (int k = 0; k < 10; k++) xi[k] = x[i * 10 + k];
  float di = dinv[i];
#pragma unroll
  for (int j = 0; j < 16; j++) {
    float acc = 0.f;
#pragma unroll
    for (int k = 0; k < 10; k++) acc = fmaf(xi[k], w[k * 16 + j], acc);
    float v = acc * di;
    hs1[i * 16 + j] = v;
    agg1[i * 16 + j] = v;
  }
}

// 4 threads per edge, each handles 4 of 16 features
__global__ void k_scatter1(const int* __restrict__ src, const int* __restrict__ dst,
                           const float* __restrict__ hs1, float* __restrict__ agg1, int e) {
  int tid = blockIdx.x * blockDim.x + threadIdx.x;
  int eid = tid >> 2;
  int c = tid & 3;
  if (eid >= e) return;
  int s = src[eid];
  int d = dst[eid];
  float4 v = *(const float4*)(hs1 + s * 16 + c * 4);
  float* p = agg1 + d * 16 + c * 4;
  atomicAdd(p + 0, v.x);
  atomicAdd(p + 1, v.y);
  atomicAdd(p + 2, v.z);
  atomicAdd(p + 3, v.w);
}

// a = relu(dinv*agg1 + b1) ; h2 = a @ W2 ; hs2 = h2*dinv ; agg2 = hs2
__global__ void k_layer2(const float* __restrict__ agg1, const float* __restrict__ dinv,
                         const float* __restrict__ b1, const float* __restrict__ W2,
                         float* __restrict__ hs2, float* __restrict__ agg2, int n) {
  __shared__ float w2[32];
  __shared__ float sb1[16];
  int t = threadIdx.x;
  if (t < 32) w2[t] = W2[t];
  if (t < 16) sb1[t] = b1[t];
  __syncthreads();
  int i = blockIdx.x * blockDim.x + t;
  if (i >= n) return;
  float di = dinv[i];
  float h0 = 0.f, h1 = 0.f;
#pragma unroll
  for (int j = 0; j < 16; j++) {
    float a = fmaxf(fmaf(di, agg1[i * 16 + j], sb1[j]), 0.f);
    h0 = fmaf(a, w2[j * 2 + 0], h0);
    h1 = fmaf(a, w2[j * 2 + 1], h1);
  }
  h0 *= di;
  h1 *= di;
  hs2[i * 2 + 0] = h0;
  hs2[i * 2 + 1] = h1;
  agg2[i * 2 + 0] = h0;
  agg2[i * 2 + 1] = h1;
}

__global__ void k_scatter2(const int* __restrict__ src, const int* __restrict__ dst,
                           const float* __restrict__ hs2, float* __restrict__ agg2, int e) {
  int i = blockIdx.x * blockDim.x + threadIdx.x;
  if (i >= e) return;
  int s = src[i];
  int d = dst[i];
  float2 v = *(const float2*)(hs2 + s * 2);
  float* p = agg2 + d * 2;
  atomicAdd(p + 0, v.x);
  atomicAdd(p + 1, v.y);
}

__global__ void k_finish(const float* __restrict__ agg2, const float* __restrict__ dinv,
                         const float* __restrict__ b2, float* __restrict__ out, int n) {
  int i = blockIdx.x * blockDim.x + threadIdx.x;
  if (i >= n) return;
  float di = dinv[i];
  out[i * 2 + 0] = fmaf(di, agg2[i * 2 + 0], b2[0]);
  out[i * 2 + 1] = fmaf(di, agg2[i * 2 + 1], b2[1]);
}

extern "C" void kernel_launch(void* const* d_in, const int* in_sizes, int n_in,
                              void* d_out, int out_size, void* d_ws, size_t ws_size,
                              hipStream_t stream) {
  const float* x  = (const float*)d_in[0];
  const int*   ei = (const int*)d_in[1];
  const float* W1 = (const float*)d_in[2];
  const float* b1 = (const float*)d_in[3];
  const float* W2 = (const float*)d_in[4];
  const float* b2 = (const float*)d_in[5];
  float* out = (float*)d_out;

  const int n = in_sizes[0] / 10;      // 200000
  const int e = in_sizes[1] / 2;       // 6400000
  const int* src = ei;
  const int* dst = ei + e;

  // workspace layout (floats)
  float* ws   = (float*)d_ws;
  float* dinv = ws;                    // n
  float* hs1  = dinv + n;              // n*16
  float* agg1 = hs1 + (size_t)n * 16;  // n*16
  float* hs2  = agg1 + (size_t)n * 16; // n*2
  float* agg2 = hs2 + (size_t)n * 2;   // n*2

  int gN = (n + BLK - 1) / BLK;
  int gE = (e + BLK - 1) / BLK;
  int gE4 = (e * 4 + BLK - 1) / BLK;

  k_deg_init<<<gN, BLK, 0, stream>>>(dinv, n);
  k_deg_count<<<gE, BLK, 0, stream>>>(dst, dinv, e);
  k_dinv<<<gN, BLK, 0, stream>>>(dinv, n);
  k_transform1<<<gN, BLK, 0, stream>>>(x, W1, dinv, hs1, agg1, n);
  k_scatter1<<<gE4, BLK, 0, stream>>>(src, dst, hs1, agg1, e);
  k_layer2<<<gN, BLK, 0, stream>>>(agg1, dinv, b1, W2, hs2, agg2, n);
  k_scatter2<<<gE, BLK, 0, stream>>>(src, dst, hs2, agg2, e);
  k_finish<<<gN, BLK, 0, stream>>>(agg2, dinv, b2, out, n);
}

// Round 2
// 1163.335 us; speedup vs baseline: 1.9844x; 1.9844x over previous
//
#include <hip/hip_runtime.h>

#define BLK 256

// ---------- CSR build ----------

__global__ void k_zero_i(int* __restrict__ p, int n) {
  int i = blockIdx.x * blockDim.x + threadIdx.x;
  if (i < n) p[i] = 0;
}

__global__ void k_hist(const int* __restrict__ dst, int* __restrict__ cnt, int e) {
  int i = blockIdx.x * blockDim.x + threadIdx.x;
  if (i < e) atomicAdd(&cnt[dst[i]], 1);
}

__global__ void k_dinv_from_cnt(const int* __restrict__ cnt, float* __restrict__ dinv, int n) {
  int i = blockIdx.x * blockDim.x + threadIdx.x;
  if (i < n) dinv[i] = rsqrtf((float)cnt[i] + 1.0f);   // deg = in-degree + self-loop
}

// per-block exclusive scan (256 elems/block), writes block totals
__global__ void k_scan_block(const int* __restrict__ cnt, int* __restrict__ off,
                             int* __restrict__ bsum, int n) {
  __shared__ int s[256];
  int t = threadIdx.x;
  int i = blockIdx.x * 256 + t;
  int v = (i < n) ? cnt[i] : 0;
  s[t] = v;
  __syncthreads();
  for (int d = 1; d < 256; d <<= 1) {
    int u = (t >= d) ? s[t - d] : 0;
    __syncthreads();
    s[t] += u;
    __syncthreads();
  }
  if (i < n) off[i] = s[t] - v;            // exclusive within block
  if (t == 255) bsum[blockIdx.x] = s[255]; // block total
}

// single-block exclusive scan of block sums (nb <= 1024)
__global__ void k_scan_sums(int* __restrict__ bsum, int nb) {
  __shared__ int s[1024];
  int t = threadIdx.x;
  int v = (t < nb) ? bsum[t] : 0;
  s[t] = v;
  __syncthreads();
  for (int d = 1; d < 1024; d <<= 1) {
    int u = (t >= d) ? s[t - d] : 0;
    __syncthreads();
    s[t] += u;
    __syncthreads();
  }
  if (t < nb) bsum[t] = s[t] - v;          // exclusive
}

__global__ void k_scan_add(int* __restrict__ off, const int* __restrict__ bsum, int n, int e) {
  int i = blockIdx.x * blockDim.x + threadIdx.x;
  if (i < n) off[i] += bsum[i >> 8];
  if (i == 0) off[n] = e;
}

__global__ void k_copy_i(const int* __restrict__ a, int* __restrict__ b, int n) {
  int i = blockIdx.x * blockDim.x + threadIdx.x;
  if (i < n) b[i] = a[i];
}

__global__ void k_fill(const int* __restrict__ src, const int* __restrict__ dst,
                       int* __restrict__ cursor, int* __restrict__ csr, int e) {
  int i = blockIdx.x * blockDim.x + threadIdx.x;
  if (i >= e) return;
  int d = dst[i];
  int p = atomicAdd(&cursor[d], 1);
  csr[p] = src[i];
}

// ---------- layer math ----------

// hs1 = (x @ W1) * dinv   (pre-scaled messages; self term handled in gather)
__global__ void k_transform1(const float* __restrict__ x, const float* __restrict__ W1,
                             const float* __restrict__ dinv, float* __restrict__ hs1, int n) {
  __shared__ float w[160];
  int t = threadIdx.x;
  if (t < 160) w[t] = W1[t];
  __syncthreads();
  int i = blockIdx.x * blockDim.x + t;
  if (i >= n) return;
  float xi[10];
#pragma unroll
  for (int k = 0; k < 10; k++) xi[k] = x[i * 10 + k];
  float di = dinv[i];
#pragma unroll
  for (int j = 0; j < 16; j++) {
    float acc = 0.f;
#pragma unroll
    for (int k = 0; k < 10; k++) acc = fmaf(xi[k], w[k * 16 + j], acc);
    hs1[i * 16 + j] = acc * di;
  }
}

// 4 lanes per node, each owns 4 features. Gather neighbor sum + self, then fused:
// a = relu(dinv*agg + b1); h2 = a @ W2; hs2 = h2 * dinv. Shuffle-reduce the 2 outputs.
__global__ void k_gather1(const int* __restrict__ off, const int* __restrict__ csr,
                          const float* __restrict__ hs1, const float* __restrict__ dinv,
                          const float* __restrict__ b1, const float* __restrict__ W2,
                          float* __restrict__ hs2, int n) {
  __shared__ float w2[32];
  __shared__ float sb1[16];
  int t = threadIdx.x;
  if (t < 32) w2[t] = W2[t];
  if (t < 16) sb1[t] = b1[t];
  __syncthreads();
  int gid = blockIdx.x * blockDim.x + t;
  int v = gid >> 2;
  int c = gid & 3;
  if (v >= n) return;
  int p0 = off[v], p1 = off[v + 1];
  float4 acc = *(const float4*)(hs1 + (size_t)v * 16 + c * 4);  // self-loop term
  for (int p = p0; p < p1; p++) {
    int s = csr[p];
    float4 m = *(const float4*)(hs1 + (size_t)s * 16 + c * 4);
    acc.x += m.x; acc.y += m.y; acc.z += m.z; acc.w += m.w;
  }
  float di = dinv[v];
  int j = c * 4;
  float a0 = fmaxf(fmaf(di, acc.x, sb1[j + 0]), 0.f);
  float a1 = fmaxf(fmaf(di, acc.y, sb1[j + 1]), 0.f);
  float a2 = fmaxf(fmaf(di, acc.z, sb1[j + 2]), 0.f);
  float a3 = fmaxf(fmaf(di, acc.w, sb1[j + 3]), 0.f);
  float h0 = a0 * w2[(j + 0) * 2] + a1 * w2[(j + 1) * 2] + a2 * w2[(j + 2) * 2] + a3 * w2[(j + 3) * 2];
  float h1 = a0 * w2[(j + 0) * 2 + 1] + a1 * w2[(j + 1) * 2 + 1] + a2 * w2[(j + 2) * 2 + 1] + a3 * w2[(j + 3) * 2 + 1];
  h0 += __shfl_xor(h0, 1); h0 += __shfl_xor(h0, 2);
  h1 += __shfl_xor(h1, 1); h1 += __shfl_xor(h1, 2);
  if (c == 0) {
    hs2[(size_t)v * 2 + 0] = h0 * di;
    hs2[(size_t)v * 2 + 1] = h1 * di;
  }
}

// 1 thread per node: out = dinv * (hs2[v] + sum_neighbors hs2[s]) + b2
__global__ void k_gather2(const int* __restrict__ off, const int* __restrict__ csr,
                          const float* __restrict__ hs2, const float* __restrict__ dinv,
                          const float* __restrict__ b2, float* __restrict__ out, int n) {
  int v = blockIdx.x * blockDim.x + threadIdx.x;
  if (v >= n) return;
  int p0 = off[v], p1 = off[v + 1];
  float2 acc = *(const float2*)(hs2 + (size_t)v * 2);  // self
  for (int p = p0; p < p1; p++) {
    int s = csr[p];
    float2 m = *(const float2*)(hs2 + (size_t)s * 2);
    acc.x += m.x; acc.y += m.y;
  }
  float di = dinv[v];
  out[(size_t)v * 2 + 0] = fmaf(di, acc.x, b2[0]);
  out[(size_t)v * 2 + 1] = fmaf(di, acc.y, b2[1]);
}

extern "C" void kernel_launch(void* const* d_in, const int* in_sizes, int n_in,
                              void* d_out, int out_size, void* d_ws, size_t ws_size,
                              hipStream_t stream) {
  const float* x  = (const float*)d_in[0];
  const int*   ei = (const int*)d_in[1];
  const float* W1 = (const float*)d_in[2];
  const float* b1 = (const float*)d_in[3];
  const float* W2 = (const float*)d_in[4];
  const float* b2 = (const float*)d_in[5];
  float* out = (float*)d_out;

  const int n = in_sizes[0] / 10;   // 200000
  const int e = in_sizes[1] / 2;    // 6400000
  const int* src = ei;
  const int* dst = ei + e;

  // workspace layout
  char* ws = (char*)d_ws;
  int*   cnt  = (int*)ws;                       ws += (size_t)n * 4;        // histogram, then reused as cursor
  int*   off  = (int*)ws;                       ws += ((size_t)n + 1) * 4;
  int*   bsum = (int*)ws;                       ws += 1024 * 4;
  int*   csr  = (int*)ws;                       ws += (size_t)e * 4;
  float* dinv = (float*)ws;                     ws += (size_t)n * 4;
  float* hs1  = (float*)ws;                     ws += (size_t)n * 16 * 4;
  float* hs2  = (float*)ws;                     ws += (size_t)n * 2 * 4;

  int gN  = (n + BLK - 1) / BLK;
  int gE  = (e + BLK - 1) / BLK;
  int nb1 = (n + 255) / 256;   // scan blocks (782 <= 1024)

  k_zero_i<<<gN, BLK, 0, stream>>>(cnt, n);
  k_hist<<<gE, BLK, 0, stream>>>(dst, cnt, e);
  k_dinv_from_cnt<<<gN, BLK, 0, stream>>>(cnt, dinv, n);
  k_scan_block<<<nb1, 256, 0, stream>>>(cnt, off, bsum, n);
  k_scan_sums<<<1, 1024, 0, stream>>>(bsum, nb1);
  k_scan_add<<<gN, BLK, 0, stream>>>(off, bsum, n, e);
  k_copy_i<<<gN, BLK, 0, stream>>>(off, cnt, n);           // cnt becomes fill cursor
  k_fill<<<gE, BLK, 0, stream>>>(src, dst, cnt, csr, e);
  k_transform1<<<gN, BLK, 0, stream>>>(x, W1, dinv, hs1, n);
  k_gather1<<<(n * 4 + BLK - 1) / BLK, BLK, 0, stream>>>(off, csr, hs1, dinv, b1, W2, hs2, n);
  k_gather2<<<gN, BLK, 0, stream>>>(off, csr, hs2, dinv, b2, out, n);
}

// Round 3
// 860.169 us; speedup vs baseline: 2.6838x; 1.3524x over previous
//
#include <hip/hip_runtime.h>

#define BLK 256
#define NB 500       // buckets; NB*BW == 200000
#define BW 400       // nodes per bucket
#define CHUNK 8192   // edges per binning block

// ---------- bucket CSR-lite build ----------

__global__ void k_zero_i(int* __restrict__ p, int n) {
  int i = blockIdx.x * blockDim.x + threadIdx.x;
  if (i < n) p[i] = 0;
}

// per-block LDS histogram of dst-buckets, one global add per bucket
__global__ void k_hist_buckets(const int* __restrict__ dst, int e, int* __restrict__ gcnt) {
  __shared__ int h[NB];
  for (int i = threadIdx.x; i < NB; i += BLK) h[i] = 0;
  __syncthreads();
  int base = blockIdx.x * CHUNK;
  for (int k = 0; k < CHUNK; k += BLK) {
    int i = base + k + threadIdx.x;
    if (i < e) atomicAdd(&h[dst[i] / BW], 1);
  }
  __syncthreads();
  for (int b = threadIdx.x; b < NB; b += BLK) {
    int c = h[b];
    if (c) atomicAdd(&gcnt[b], c);
  }
}

// exclusive scan of gcnt[NB] -> gbase[NB+1]; init gcursor
__global__ void k_scan_buckets(const int* __restrict__ gcnt, int* __restrict__ gbase,
                               int* __restrict__ gcursor, int e) {
  __shared__ int s[512];
  int t = threadIdx.x;
  int v = (t < NB) ? gcnt[t] : 0;
  s[t] = v;
  __syncthreads();
  for (int d = 1; d < 512; d <<= 1) {
    int u = (t >= d) ? s[t - d] : 0;
    __syncthreads();
    s[t] += u;
    __syncthreads();
  }
  if (t < NB) { int ex = s[t] - v; gbase[t] = ex; gcursor[t] = ex; }
  if (t == 0) gbase[NB] = e;
}

// bin edges: pack src(18b) | dst_local(9b) into uint32, contiguous per-block runs per bucket
__global__ void k_bin(const int* __restrict__ src, const int* __restrict__ dst, int e,
                      int* __restrict__ gcursor, unsigned* __restrict__ binned) {
  __shared__ int lcnt[NB];
  __shared__ int lbase[NB];
  int t = threadIdx.x;
  for (int i = t; i < NB; i += BLK) lcnt[i] = 0;
  __syncthreads();
  int base = blockIdx.x * CHUNK;
  for (int k = 0; k < CHUNK; k += BLK) {
    int i = base + k + t;
    if (i < e) atomicAdd(&lcnt[dst[i] / BW], 1);
  }
  __syncthreads();
  for (int b = t; b < NB; b += BLK) {
    int c = lcnt[b];
    lbase[b] = c ? atomicAdd(&gcursor[b], c) : 0;
    lcnt[b] = 0;
  }
  __syncthreads();
  for (int k = 0; k < CHUNK; k += BLK) {
    int i = base + k + t;
    if (i < e) {
      int d = dst[i];
      int b = d / BW;
      int dl = d - b * BW;
      int pos = atomicAdd(&lcnt[b], 1);
      binned[lbase[b] + pos] = (unsigned)src[i] | ((unsigned)dl << 18);
    }
  }
}

// per-bucket degree -> dinv (deg = in-degree + 1 self-loop)
__global__ void k_ldeg(const unsigned* __restrict__ binned, const int* __restrict__ gbase,
                       float* __restrict__ dinv) {
  __shared__ int cnt[BW];
  int t = threadIdx.x;
  for (int i = t; i < BW; i += BLK) cnt[i] = 0;
  __syncthreads();
  int b = blockIdx.x;
  int p0 = gbase[b], p1 = gbase[b + 1];
  for (int p = p0 + t; p < p1; p += BLK) atomicAdd(&cnt[binned[p] >> 18], 1);
  __syncthreads();
  for (int i = t; i < BW; i += BLK) dinv[b * BW + i] = rsqrtf((float)cnt[i] + 1.0f);
}

// ---------- layer math ----------

// hs1 = (x @ W1) * dinv
__global__ void k_transform1(const float* __restrict__ x, const float* __restrict__ W1,
                             const float* __restrict__ dinv, float* __restrict__ hs1, int n) {
  __shared__ float w[160];
  int t = threadIdx.x;
  if (t < 160) w[t] = W1[t];
  __syncthreads();
  int i = blockIdx.x * blockDim.x + t;
  if (i >= n) return;
  float xi[10];
#pragma unroll
  for (int k = 0; k < 10; k++) xi[k] = x[i * 10 + k];
  float di = dinv[i];
#pragma unroll
  for (int j = 0; j < 16; j++) {
    float acc = 0.f;
#pragma unroll
    for (int k = 0; k < 10; k++) acc = fmaf(xi[k], w[k * 16 + j], acc);
    hs1[(size_t)i * 16 + j] = acc * di;
  }
}

// one block per bucket: LDS-accumulate layer-1 messages, fuse layer-2 transform
__global__ void __launch_bounds__(BLK) k_agg1(const unsigned* __restrict__ binned,
                                              const int* __restrict__ gbase,
                                              const float* __restrict__ hs1,
                                              const float* __restrict__ dinv,
                                              const float* __restrict__ b1,
                                              const float* __restrict__ W2,
                                              float* __restrict__ hs2) {
  __shared__ float agg[BW * 16];   // 25.6 KB
  __shared__ float w2[32];
  __shared__ float sb1[16];
  int t = threadIdx.x;
  if (t < 32) w2[t] = W2[t];
  if (t < 16) sb1[t] = b1[t];
  for (int i = t; i < BW * 16; i += BLK) agg[i] = 0.f;
  __syncthreads();
  int bkt = blockIdx.x;
  int p0 = gbase[bkt], p1 = gbase[bkt + 1];
  int c = t & 3;                                 // feature quarter
  for (int p = p0 + (t >> 2); p < p1; p += BLK / 4) {
    unsigned pk = binned[p];
    int s = pk & 0x3FFFF;
    int dl = pk >> 18;
    float4 m = *(const float4*)(hs1 + (size_t)s * 16 + c * 4);
    float* a = agg + dl * 16 + c * 4;
    atomicAdd(a + 0, m.x);
    atomicAdd(a + 1, m.y);
    atomicAdd(a + 2, m.z);
    atomicAdd(a + 3, m.w);
  }
  __syncthreads();
  for (int vl = t; vl < BW; vl += BLK) {
    int v = bkt * BW + vl;
    float di = dinv[v];
    float h0 = 0.f, h1 = 0.f;
#pragma unroll
    for (int j = 0; j < 16; j++) {
      float sum = agg[vl * 16 + j] + hs1[(size_t)v * 16 + j];  // + self-loop
      float a = fmaxf(fmaf(di, sum, sb1[j]), 0.f);
      h0 = fmaf(a, w2[j * 2 + 0], h0);
      h1 = fmaf(a, w2[j * 2 + 1], h1);
    }
    hs2[(size_t)v * 2 + 0] = h0 * di;
    hs2[(size_t)v * 2 + 1] = h1 * di;
  }
}

// one block per bucket: layer-2 aggregate + output
__global__ void k_agg2(const unsigned* __restrict__ binned, const int* __restrict__ gbase,
                       const float* __restrict__ hs2, const float* __restrict__ dinv,
                       const float* __restrict__ b2, float* __restrict__ out) {
  __shared__ float agg[BW * 2];
  int t = threadIdx.x;
  for (int i = t; i < BW * 2; i += BLK) agg[i] = 0.f;
  __syncthreads();
  int bkt = blockIdx.x;
  int p0 = gbase[bkt], p1 = gbase[bkt + 1];
  for (int p = p0 + t; p < p1; p += BLK) {
    unsigned pk = binned[p];
    int s = pk & 0x3FFFF;
    int dl = pk >> 18;
    float2 m = *(const float2*)(hs2 + (size_t)s * 2);
    atomicAdd(&agg[dl * 2 + 0], m.x);
    atomicAdd(&agg[dl * 2 + 1], m.y);
  }
  __syncthreads();
  float B0 = b2[0], B1 = b2[1];
  for (int vl = t; vl < BW; vl += BLK) {
    int v = bkt * BW + vl;
    float di = dinv[v];
    out[(size_t)v * 2 + 0] = fmaf(di, agg[vl * 2 + 0] + hs2[(size_t)v * 2 + 0], B0);
    out[(size_t)v * 2 + 1] = fmaf(di, agg[vl * 2 + 1] + hs2[(size_t)v * 2 + 1], B1);
  }
}

extern "C" void kernel_launch(void* const* d_in, const int* in_sizes, int n_in,
                              void* d_out, int out_size, void* d_ws, size_t ws_size,
                              hipStream_t stream) {
  const float* x  = (const float*)d_in[0];
  const int*   ei = (const int*)d_in[1];
  const float* W1 = (const float*)d_in[2];
  const float* b1 = (const float*)d_in[3];
  const float* W2 = (const float*)d_in[4];
  const float* b2 = (const float*)d_in[5];
  float* out = (float*)d_out;

  const int n = in_sizes[0] / 10;   // 200000
  const int e = in_sizes[1] / 2;    // 6400000
  const int* src = ei;
  const int* dst = ei + e;

  // workspace layout
  char* ws = (char*)d_ws;
  int*      gcnt    = (int*)ws;      ws += (size_t)NB * 4;
  int*      gbase   = (int*)ws;      ws += ((size_t)NB + 1) * 4;
  int*      gcursor = (int*)ws;      ws += (size_t)NB * 4;
  unsigned* binned  = (unsigned*)ws; ws += (size_t)e * 4;
  float*    dinv    = (float*)ws;    ws += (size_t)n * 4;
  float*    hs1     = (float*)ws;    ws += (size_t)n * 16 * 4;
  float*    hs2     = (float*)ws;    ws += (size_t)n * 2 * 4;

  int gN = (n + BLK - 1) / BLK;
  int gC = (e + CHUNK - 1) / CHUNK;   // 782 binning blocks

  k_zero_i<<<(NB + BLK - 1) / BLK, BLK, 0, stream>>>(gcnt, NB);
  k_hist_buckets<<<gC, BLK, 0, stream>>>(dst, e, gcnt);
  k_scan_buckets<<<1, 512, 0, stream>>>(gcnt, gbase, gcursor, e);
  k_bin<<<gC, BLK, 0, stream>>>(src, dst, e, gcursor, binned);
  k_ldeg<<<NB, BLK, 0, stream>>>(binned, gbase, dinv);
  k_transform1<<<gN, BLK, 0, stream>>>(x, W1, dinv, hs1, n);
  k_agg1<<<NB, BLK, 0, stream>>>(binned, gbase, hs1, dinv, b1, W2, hs2);
  k_agg2<<<NB, BLK, 0, stream>>>(binned, gbase, hs2, dinv, b2, out);
}